// Round 6
// baseline (255.948 us; speedup 1.0000x reference)
//
#include <hip/hip_runtime.h>

#define D_IN 128
#define D_H 256
#define D_OUT 128
#define N_SETS 8192
#define T_TOTAL 262144
#define N_CHUNKS 683          // ceil(262144 / 384)

typedef short short8 __attribute__((ext_vector_type(8)));
typedef float floatx4 __attribute__((ext_vector_type(4)));
typedef float floatx16 __attribute__((ext_vector_type(16)));
typedef unsigned int uint4v __attribute__((ext_vector_type(4)));

typedef const __attribute__((address_space(1))) unsigned int gu32;
typedef __attribute__((address_space(3))) unsigned int lu32;

union U8 { uint4v u; short8 s; };

__device__ inline unsigned short f32_bf16(float f) {
    unsigned int u = __float_as_uint(f);
    u += 0x7FFFu + ((u >> 16) & 1u);   // round-to-nearest-even
    return (unsigned short)(u >> 16);
}

// Setup: swizzle W1/W2 into 32x32x16 MFMA fragment order (zeroing via memset).
// Frag = 64 lanes x 8 bf16 (16B/lane).
// W1 frag f = nt*8 + c  (nt<8 coltile, c<8 kstep):  lane l, j:
//   W1[k = c*16 + (l>>5)*8 + j][col = nt*32 + (l&31)]
// W2 frag f = 64 + o*16 + c2 (o<4, c2<16): W2[k = c2*16 + (l>>5)*8 + j][col = o*32 + (l&31)]
__global__ void setup_kernel(const float* __restrict__ W1, const float* __restrict__ W2,
                             unsigned short* __restrict__ W1s, unsigned short* __restrict__ W2s) {
    int t = blockIdx.x * 256 + threadIdx.x;
    int l = t & 63;
    int f = t >> 6;                      // 0..127
    int hl = l >> 5, c31 = l & 31;
    if (f < 64) {                        // W1: 8 col-tiles x 8 k-steps
        int nt = f >> 3, c = f & 7;
        int k0 = c * 16 + hl * 8, n = nt * 32 + c31;
        unsigned short v[8];
#pragma unroll
        for (int j = 0; j < 8; j++) v[j] = f32_bf16(W1[(k0 + j) * D_H + n]);
#pragma unroll
        for (int j = 0; j < 8; j++) W1s[f * 512 + l * 8 + j] = v[j];
    } else {                             // W2: 4 col-tiles x 16 k-steps
        int g = f - 64;
        int o = g >> 4, c2 = g & 15;
        int k0 = c2 * 16 + hl * 8, n = o * 32 + c31;
        unsigned short v[8];
#pragma unroll
        for (int j = 0; j < 8; j++) v[j] = f32_bf16(W2[(k0 + j) * D_OUT + n]);
#pragma unroll
        for (int j = 0; j < 8; j++) W2s[g * 512 + l * 8 + j] = v[j];
    }
}

// R6: PERSISTENT BLOCKS. R5's counters fit "per-wave chain x zero overlap":
// 1 block/CU ran as 2.67 sequential generations (stage 128KB -> barrier ->
// all 12 waves stall in lock-phase -> epilogue drain -> next block restages).
// Now: grid=256 (1/CU), weights staged ONCE per CU, one barrier EVER, then
// each block grid-strides 683 chunks of 384 tokens with NO barriers: waves
// de-phase so DS/MFMA stalls interleave; x-loads of chunk k+1 overlap the
// epilogue of chunk k. Compute core identical to R5 (in-register layer
// handoff via 32x32x16 MFMA + cvt_pk + permlane32_swap; zero slab).
__global__ __launch_bounds__(768, 3) void ds_main(
    const float* __restrict__ x, const int* __restrict__ seg,
    const unsigned short* __restrict__ W1s, const float* __restrict__ b1,
    const unsigned short* __restrict__ W2s, const float* __restrict__ b2,
    float* __restrict__ out, float* __restrict__ counts)
{
    __shared__ __align__(16) unsigned short wbuf[128 * 512];     // 128 KB: frags 0..63 W1, 64..127 W2
    __shared__ int ssegs[12][32];

    const int tid = threadIdx.x;
    const int wave = tid >> 6, lane = tid & 63;
    const int hl = lane >> 5, c31 = lane & 31;

    // ---- one-time weight staging by waves 0..7 (16B/lane, linear) ----
    if (wave < 8) {
#pragma unroll
        for (int i = 0; i < 8; i++) {
            __builtin_amdgcn_global_load_lds((gu32*)(W1s + i * 4096 + tid * 8),
                                             (lu32*)(wbuf + i * 4096 + tid * 8), 16, 0, 0);
            __builtin_amdgcn_global_load_lds((gu32*)(W2s + i * 4096 + tid * 8),
                                             (lu32*)(wbuf + 32768 + i * 4096 + tid * 8), 16, 0, 0);
        }
    }

    int* sseg = ssegs[wave];

    __syncthreads();   // weights staged; the ONLY barrier in the kernel

    // ---- persistent chunk loop: no barriers, waves fully independent ----
    for (int chunk = blockIdx.x; chunk < N_CHUNKS; chunk += 256) {
        const int tok0 = chunk * 384 + wave * 32;
        if (tok0 >= T_TOTAL) continue;             // wave-uniform tail guard

        if (lane < 32) sseg[lane] = seg[tok0 + lane];

        // ---- x fragments (fp32 -> bf16 via cvt_pk): lane = tok c31, k = c*16 + hl*8 + j ----
        short8 xfa[8];
        {
            const float* xp = x + (size_t)(tok0 + c31) * D_IN + hl * 8;
#pragma unroll
            for (int c = 0; c < 8; c++) {
                float4 v0 = *(const float4*)(xp + c * 16);
                float4 v1 = *(const float4*)(xp + c * 16 + 4);
                unsigned int p0, p1, p2, p3;
                asm("v_cvt_pk_bf16_f32 %0, %1, %2" : "=v"(p0) : "v"(v0.x), "v"(v0.y));
                asm("v_cvt_pk_bf16_f32 %0, %1, %2" : "=v"(p1) : "v"(v0.z), "v"(v0.w));
                asm("v_cvt_pk_bf16_f32 %0, %1, %2" : "=v"(p2) : "v"(v1.x), "v"(v1.y));
                asm("v_cvt_pk_bf16_f32 %0, %1, %2" : "=v"(p3) : "v"(v1.z), "v"(v1.w));
                U8 u; u.u = (uint4v){p0, p1, p2, p3};
                xfa[c] = u.s;
            }
        }

        floatx16 acc2[4];
#pragma unroll
        for (int o = 0; o < 4; o++)
#pragma unroll
            for (int i = 0; i < 16; i++) acc2[o][i] = 0.f;

        // ---- fused pipeline over 8 h1 col-tiles (32 cols each) ----
#pragma unroll
        for (int nt = 0; nt < 8; nt++) {
            // layer 1: acc1 = W1^T-tile x x^T  (D: col=lane&31=tok, row=h1col pattern)
            floatx16 acc1;
#pragma unroll
            for (int i = 0; i < 16; i++) acc1[i] = 0.f;
#pragma unroll
            for (int c = 0; c < 8; c++) {
                short8 wf = *(const short8*)(wbuf + (nt * 8 + c) * 512 + lane * 8);
                acc1 = __builtin_amdgcn_mfma_f32_32x32x16_bf16(wf, xfa[c], acc1, 0, 0, 0);
            }
            // bias + relu: reg r -> h1col = nt*32 + (r&3) + 8*(r>>2) + 4*hl
            float v[16];
#pragma unroll
            for (int g = 0; g < 4; g++) {
                floatx4 bv = *(const floatx4*)(b1 + nt * 32 + g * 8 + hl * 4);
#pragma unroll
                for (int i = 0; i < 4; i++) v[g * 4 + i] = fmaxf(acc1[g * 4 + i] + bv[i], 0.f);
            }
            // pack pairs: pk[p] = bf16(v[2p]) | bf16(v[2p+1])<<16
            unsigned int pk[8];
#pragma unroll
            for (int p = 0; p < 8; p++)
                asm("v_cvt_pk_bf16_f32 %0, %1, %2" : "=v"(pk[p]) : "v"(v[2 * p]), "v"(v[2 * p + 1]));
            // assemble layer-2 A-frags (k = c2*16 + hl*8 + {0..7}) via permlane32_swap, then MFMA
#pragma unroll
            for (int s = 0; s < 2; s++) {
                unsigned int d0 = pk[s * 4 + 0], d2 = pk[s * 4 + 2];
                asm("v_permlane32_swap_b32 %0, %1" : "+v"(d0), "+v"(d2));
                unsigned int d1 = pk[s * 4 + 1], d3 = pk[s * 4 + 3];
                asm("v_permlane32_swap_b32 %0, %1" : "+v"(d1), "+v"(d3));
                U8 u; u.u = (uint4v){d0, d1, d2, d3};
                const short8 hf = u.s;
                const int c2 = nt * 2 + s;
#pragma unroll
                for (int o = 0; o < 4; o++) {
                    short8 bw = *(const short8*)(wbuf + (64 + o * 16 + c2) * 512 + lane * 8);
                    acc2[o] = __builtin_amdgcn_mfma_f32_32x32x16_bf16(hf, bw, acc2[o], 0, 0, 0);
                }
            }
        }

        // ---- counts: run heads within this wave's 32 tokens ----
        if (lane < 32) {
            int s = sseg[lane];
            if (lane == 0 || sseg[lane - 1] != s) {
                int len = 1;
                for (int u = lane + 1; u < 32 && sseg[u] == s; ++u) ++len;
                atomicAdd(&counts[s], (float)len);
            }
        }

        // ---- epilogue: lane owns outcol per o-tile; swaps -> contiguous 16 toks; run-scan ----
        int sid[16];
#pragma unroll
        for (int e = 0; e < 16; e++) sid[e] = sseg[hl * 16 + e];

#pragma unroll
        for (int o = 0; o < 4; o++) {
            const float bias = b2[o * 32 + c31];
            float val[16];
#pragma unroll
            for (int r = 0; r < 16; r++) val[r] = fmaxf(acc2[o][r] + bias, 0.f);
            // regs -> token order: lo-lanes toks 0..15, hi-lanes 16..31
            float st[16];
#pragma unroll
            for (int i = 0; i < 4; i++) {
                float a = val[i], b = val[8 + i];
                asm("v_permlane32_swap_b32 %0, %1" : "+v"(a), "+v"(b));
                st[i] = a; st[4 + i] = b;
                float c = val[4 + i], d = val[12 + i];
                asm("v_permlane32_swap_b32 %0, %1" : "+v"(c), "+v"(d));
                st[8 + i] = c; st[12 + i] = d;
            }
            const int col = o * 32 + c31;
            float sum = st[0];
#pragma unroll
            for (int e = 1; e < 16; e++) {
                if (sid[e] != sid[e - 1]) {
                    atomicAdd(&out[(size_t)sid[e - 1] * D_OUT + col], sum);
                    sum = 0.f;
                }
                sum += st[e];
            }
            atomicAdd(&out[(size_t)sid[15] * D_OUT + col], sum);
        }
    }
}

__global__ void div_kernel(float4* __restrict__ out4, const float* __restrict__ counts) {
    int i = blockIdx.x * 256 + threadIdx.x;   // 262144 float4s, 32 per row
    float inv = 1.f / fmaxf(counts[i >> 5], 1.f);
    float4 v = out4[i];
    v.x *= inv; v.y *= inv; v.z *= inv; v.w *= inv;
    out4[i] = v;
}

extern "C" void kernel_launch(void* const* d_in, const int* in_sizes, int n_in,
                              void* d_out, int out_size, void* d_ws, size_t ws_size,
                              hipStream_t stream) {
    const float* x  = (const float*)d_in[0];
    const int* seg  = (const int*)d_in[1];
    const float* W1 = (const float*)d_in[3];
    const float* b1 = (const float*)d_in[4];
    const float* W2 = (const float*)d_in[5];
    const float* b2 = (const float*)d_in[6];
    float* out = (float*)d_out;

    float* counts       = (float*)d_ws;                                   // 32 KB
    unsigned short* W1s = (unsigned short*)((char*)d_ws + 32768);         // 64 KB
    unsigned short* W2s = (unsigned short*)((char*)d_ws + 32768 + 65536); // 64 KB

    hipMemsetAsync(out, 0, (size_t)N_SETS * D_OUT * sizeof(float), stream);
    hipMemsetAsync(counts, 0, (size_t)N_SETS * sizeof(float), stream);
    hipLaunchKernelGGL(setup_kernel, dim3(32), dim3(256), 0, stream,
                       W1, W2, W1s, W2s);
    hipLaunchKernelGGL(ds_main, dim3(256), dim3(768), 0, stream,
                       x, seg, W1s, b1, W2s, b2, out, counts);
    hipLaunchKernelGGL(div_kernel, dim3(1024), dim3(256), 0, stream,
                       (float4*)out, counts);
}

// Round 9
// 252.489 us; speedup vs baseline: 1.0137x; 1.0137x over previous
//
#include <hip/hip_runtime.h>

#define D_IN 128
#define D_H 256
#define D_OUT 128
#define N_SETS 8192
#define T_TOTAL 262144

typedef short short8 __attribute__((ext_vector_type(8)));
typedef float floatx4 __attribute__((ext_vector_type(4)));
typedef float floatx16 __attribute__((ext_vector_type(16)));
typedef unsigned int uint4v __attribute__((ext_vector_type(4)));

typedef const __attribute__((address_space(1))) unsigned int gu32;
typedef __attribute__((address_space(3))) unsigned int lu32;

union U8 { uint4v u; short8 s; };

__device__ inline unsigned short f32_bf16(float f) {
    unsigned int u = __float_as_uint(f);
    u += 0x7FFFu + ((u >> 16) & 1u);   // round-to-nearest-even
    return (unsigned short)(u >> 16);
}

// Setup: swizzle W1/W2 into 32x32x16 MFMA fragment order (zeroing via memset).
// W1 frag f = nt*8 + c:  lane l, j: W1[k = c*16 + (l>>5)*8 + j][col = nt*32 + (l&31)]
// W2 frag f = 64 + o*16 + c2:       W2[k = c2*16 + (l>>5)*8 + j][col = o*32 + (l&31)]
__global__ void setup_kernel(const float* __restrict__ W1, const float* __restrict__ W2,
                             unsigned short* __restrict__ W1s, unsigned short* __restrict__ W2s) {
    int t = blockIdx.x * 256 + threadIdx.x;
    int l = t & 63;
    int f = t >> 6;                      // 0..127
    int hl = l >> 5, c31 = l & 31;
    if (f < 64) {                        // W1: 8 col-tiles x 8 k-steps
        int nt = f >> 3, c = f & 7;
        int k0 = c * 16 + hl * 8, n = nt * 32 + c31;
        unsigned short v[8];
#pragma unroll
        for (int j = 0; j < 8; j++) v[j] = f32_bf16(W1[(k0 + j) * D_H + n]);
#pragma unroll
        for (int j = 0; j < 8; j++) W1s[f * 512 + l * 8 + j] = v[j];
    } else {                             // W2: 4 col-tiles x 16 k-steps
        int g = f - 64;
        int o = g >> 4, c2 = g & 15;
        int k0 = c2 * 16 + hl * 8, n = o * 32 + c31;
        unsigned short v[8];
#pragma unroll
        for (int j = 0; j < 8; j++) v[j] = f32_bf16(W2[(k0 + j) * D_OUT + n]);
#pragma unroll
        for (int j = 0; j < 8; j++) W2s[g * 512 + l * 8 + j] = v[j];
    }
}

// R9: I-CACHE experiment = R5 (best passing, 100us) + "#pragma unroll 1" on
// the nt-loop. Evidence: MFMA 13% / VALU 15% / DS ~20% / HBM 10%, flat across
// occupancy+structure; R4's CAS->native null ALSO exonerates atomic volume
// (a waiting CAS loop vs fire-and-forget changed nothing => epilogue hidden).
// Last per-CU fixed-rate suspect invisible to our counters and WORSENED by
// more waves (explains R3 null): 32KB L1I. Unrolled body ~3-5k instr (~25-40KB)
// thrashes it; 12 de-phased waves stream code from L2 at fixed rate. Rolled
// nt-loop shrinks hot code ~8x (~1.5KB, I$-resident). All inner arrays keep
// static indexing (c/o/s loops stay unrolled) - no scratch.
__global__ __launch_bounds__(768, 3) void ds_main(
    const float* __restrict__ x, const int* __restrict__ seg,
    const unsigned short* __restrict__ W1s, const float* __restrict__ b1,
    const unsigned short* __restrict__ W2s, const float* __restrict__ b2,
    float* __restrict__ out, float* __restrict__ counts)
{
    __shared__ __align__(16) unsigned short wbuf[128 * 512];     // 128 KB: frags 0..63 W1, 64..127 W2
    __shared__ int ssegs[12][32];

    const int tid = threadIdx.x;
    const int wave = tid >> 6, lane = tid & 63;
    const int hl = lane >> 5, c31 = lane & 31;
    const int tok0 = blockIdx.x * 384 + wave * 32;
    const bool active = (tok0 < T_TOTAL);          // wave-uniform tail guard

    // ---- one-time weight staging by waves 0..7 (16B/lane, linear) ----
    if (wave < 8) {
#pragma unroll
        for (int i = 0; i < 8; i++) {
            __builtin_amdgcn_global_load_lds((gu32*)(W1s + i * 4096 + tid * 8),
                                             (lu32*)(wbuf + i * 4096 + tid * 8), 16, 0, 0);
            __builtin_amdgcn_global_load_lds((gu32*)(W2s + i * 4096 + tid * 8),
                                             (lu32*)(wbuf + 32768 + i * 4096 + tid * 8), 16, 0, 0);
        }
    }

    int* sseg = ssegs[wave];

    // ---- x fragments (fp32 -> bf16 via cvt_pk): lane = tok c31, k = c*16 + hl*8 + j ----
    short8 xfa[8];
    if (active) {
        if (lane < 32) sseg[lane] = seg[tok0 + lane];
        const float* xp = x + (size_t)(tok0 + c31) * D_IN + hl * 8;
#pragma unroll
        for (int c = 0; c < 8; c++) {
            float4 v0 = *(const float4*)(xp + c * 16);
            float4 v1 = *(const float4*)(xp + c * 16 + 4);
            unsigned int p0, p1, p2, p3;
            asm("v_cvt_pk_bf16_f32 %0, %1, %2" : "=v"(p0) : "v"(v0.x), "v"(v0.y));
            asm("v_cvt_pk_bf16_f32 %0, %1, %2" : "=v"(p1) : "v"(v0.z), "v"(v0.w));
            asm("v_cvt_pk_bf16_f32 %0, %1, %2" : "=v"(p2) : "v"(v1.x), "v"(v1.y));
            asm("v_cvt_pk_bf16_f32 %0, %1, %2" : "=v"(p3) : "v"(v1.z), "v"(v1.w));
            U8 u; u.u = (uint4v){p0, p1, p2, p3};
            xfa[c] = u.s;
        }
    }

    floatx16 acc2[4];
#pragma unroll
    for (int o = 0; o < 4; o++)
#pragma unroll
        for (int i = 0; i < 16; i++) acc2[o][i] = 0.f;

    __syncthreads();   // weights staged; ONLY barrier
    if (!active) return;

    // ---- fused pipeline over 8 h1 col-tiles (ROLLED: the I$ experiment) ----
#pragma unroll 1
    for (int nt = 0; nt < 8; nt++) {
        // layer 1: acc1 = W1^T-tile x x^T  (D: col=lane&31=tok, row=h1col pattern)
        floatx16 acc1;
#pragma unroll
        for (int i = 0; i < 16; i++) acc1[i] = 0.f;
#pragma unroll
        for (int c = 0; c < 8; c++) {
            short8 wf = *(const short8*)(wbuf + (nt * 8 + c) * 512 + lane * 8);
            acc1 = __builtin_amdgcn_mfma_f32_32x32x16_bf16(wf, xfa[c], acc1, 0, 0, 0);
        }
        // bias + relu: reg r -> h1col = nt*32 + (r&3) + 8*(r>>2) + 4*hl
        float v[16];
#pragma unroll
        for (int g = 0; g < 4; g++) {
            floatx4 bv = *(const floatx4*)(b1 + nt * 32 + g * 8 + hl * 4);
#pragma unroll
            for (int i = 0; i < 4; i++) v[g * 4 + i] = fmaxf(acc1[g * 4 + i] + bv[i], 0.f);
        }
        // pack pairs: pk[p] = bf16(v[2p]) | bf16(v[2p+1])<<16
        unsigned int pk[8];
#pragma unroll
        for (int p = 0; p < 8; p++)
            asm("v_cvt_pk_bf16_f32 %0, %1, %2" : "=v"(pk[p]) : "v"(v[2 * p]), "v"(v[2 * p + 1]));
        // assemble layer-2 A-frags (k = c2*16 + hl*8 + {0..7}) via permlane32_swap, then MFMA
#pragma unroll
        for (int s = 0; s < 2; s++) {
            unsigned int d0 = pk[s * 4 + 0], d2 = pk[s * 4 + 2];
            asm("v_permlane32_swap_b32 %0, %1" : "+v"(d0), "+v"(d2));
            unsigned int d1 = pk[s * 4 + 1], d3 = pk[s * 4 + 3];
            asm("v_permlane32_swap_b32 %0, %1" : "+v"(d1), "+v"(d3));
            U8 u; u.u = (uint4v){d0, d1, d2, d3};
            const short8 hf = u.s;
            const int c2 = nt * 2 + s;
#pragma unroll
            for (int o = 0; o < 4; o++) {
                short8 bw = *(const short8*)(wbuf + (64 + o * 16 + c2) * 512 + lane * 8);
                acc2[o] = __builtin_amdgcn_mfma_f32_32x32x16_bf16(hf, bw, acc2[o], 0, 0, 0);
            }
        }
    }

    // ---- counts: run heads within this wave's 32 tokens ----
    if (lane < 32) {
        int s = sseg[lane];
        if (lane == 0 || sseg[lane - 1] != s) {
            int len = 1;
            for (int u = lane + 1; u < 32 && sseg[u] == s; ++u) ++len;
            atomicAdd(&counts[s], (float)len);
        }
    }

    // ---- epilogue: lane owns outcol per o-tile; swaps -> contiguous 16 toks; run-scan ----
    int sid[16];
#pragma unroll
    for (int e = 0; e < 16; e++) sid[e] = sseg[hl * 16 + e];

#pragma unroll
    for (int o = 0; o < 4; o++) {
        const float bias = b2[o * 32 + c31];
        float val[16];
#pragma unroll
        for (int r = 0; r < 16; r++) val[r] = fmaxf(acc2[o][r] + bias, 0.f);
        // regs -> token order: lo-lanes toks 0..15, hi-lanes 16..31
        float st[16];
#pragma unroll
        for (int i = 0; i < 4; i++) {
            float a = val[i], b = val[8 + i];
            asm("v_permlane32_swap_b32 %0, %1" : "+v"(a), "+v"(b));
            st[i] = a; st[4 + i] = b;
            float c = val[4 + i], d = val[12 + i];
            asm("v_permlane32_swap_b32 %0, %1" : "+v"(c), "+v"(d));
            st[8 + i] = c; st[12 + i] = d;
        }
        const int col = o * 32 + c31;
        float sum = st[0];
#pragma unroll
        for (int e = 1; e < 16; e++) {
            if (sid[e] != sid[e - 1]) {
                atomicAdd(&out[(size_t)sid[e - 1] * D_OUT + col], sum);
                sum = 0.f;
            }
            sum += st[e];
        }
        atomicAdd(&out[(size_t)sid[15] * D_OUT + col], sum);
    }
}

__global__ void div_kernel(float4* __restrict__ out4, const float* __restrict__ counts) {
    int i = blockIdx.x * 256 + threadIdx.x;   // 262144 float4s, 32 per row
    float inv = 1.f / fmaxf(counts[i >> 5], 1.f);
    float4 v = out4[i];
    v.x *= inv; v.y *= inv; v.z *= inv; v.w *= inv;
    out4[i] = v;
}

extern "C" void kernel_launch(void* const* d_in, const int* in_sizes, int n_in,
                              void* d_out, int out_size, void* d_ws, size_t ws_size,
                              hipStream_t stream) {
    const float* x  = (const float*)d_in[0];
    const int* seg  = (const int*)d_in[1];
    const float* W1 = (const float*)d_in[3];
    const float* b1 = (const float*)d_in[4];
    const float* W2 = (const float*)d_in[5];
    const float* b2 = (const float*)d_in[6];
    float* out = (float*)d_out;

    float* counts       = (float*)d_ws;                                   // 32 KB
    unsigned short* W1s = (unsigned short*)((char*)d_ws + 32768);         // 64 KB
    unsigned short* W2s = (unsigned short*)((char*)d_ws + 32768 + 65536); // 64 KB

    hipMemsetAsync(out, 0, (size_t)N_SETS * D_OUT * sizeof(float), stream);
    hipMemsetAsync(counts, 0, (size_t)N_SETS * sizeof(float), stream);
    hipLaunchKernelGGL(setup_kernel, dim3(32), dim3(256), 0, stream,
                       W1, W2, W1s, W2s);
    hipLaunchKernelGGL(ds_main, dim3(683), dim3(768), 0, stream,
                       x, seg, W1s, b1, W2s, b2, out, counts);
    hipLaunchKernelGGL(div_kernel, dim3(1024), dim3(256), 0, stream,
                       (float4*)out, counts);
}

// Round 10
// 245.475 us; speedup vs baseline: 1.0427x; 1.0286x over previous
//
#include <hip/hip_runtime.h>

#define D_IN 128
#define D_H 256
#define D_OUT 128
#define N_SETS 8192
#define T_TOTAL 262144

typedef short short8 __attribute__((ext_vector_type(8)));
typedef float floatx4 __attribute__((ext_vector_type(4)));
typedef float floatx16 __attribute__((ext_vector_type(16)));
typedef unsigned int uint4v __attribute__((ext_vector_type(4)));
typedef unsigned int uint2v __attribute__((ext_vector_type(2)));

typedef const __attribute__((address_space(1))) unsigned int gu32;
typedef __attribute__((address_space(3))) unsigned int lu32;

union U8 { uint4v u; short8 s; };

__device__ inline unsigned short f32_bf16(float f) {
    unsigned int u = __float_as_uint(f);
    u += 0x7FFFu + ((u >> 16) & 1u);   // round-to-nearest-even
    return (unsigned short)(u >> 16);
}

// Setup: swizzle W1/W2 into 32x32x16 MFMA fragment order (zeroing via memset).
// W1 frag f = nt*8 + c:  lane l, j: W1[k = c*16 + (l>>5)*8 + j][col = nt*32 + (l&31)]
// W2 frag f = 64 + o*16 + c2:       W2[k = c2*16 + (l>>5)*8 + j][col = o*32 + (l&31)]
__global__ void setup_kernel(const float* __restrict__ W1, const float* __restrict__ W2,
                             unsigned short* __restrict__ W1s, unsigned short* __restrict__ W2s) {
    int t = blockIdx.x * 256 + threadIdx.x;
    int l = t & 63;
    int f = t >> 6;                      // 0..127
    int hl = l >> 5, c31 = l & 31;
    if (f < 64) {                        // W1: 8 col-tiles x 8 k-steps
        int nt = f >> 3, c = f & 7;
        int k0 = c * 16 + hl * 8, n = nt * 32 + c31;
        unsigned short v[8];
#pragma unroll
        for (int j = 0; j < 8; j++) v[j] = f32_bf16(W1[(k0 + j) * D_H + n]);
#pragma unroll
        for (int j = 0; j < 8; j++) W1s[f * 512 + l * 8 + j] = v[j];
    } else {                             // W2: 4 col-tiles x 16 k-steps
        int g = f - 64;
        int o = g >> 4, c2 = g & 15;
        int k0 = c2 * 16 + hl * 8, n = o * 32 + c31;
        unsigned short v[8];
#pragma unroll
        for (int j = 0; j < 8; j++) v[j] = f32_bf16(W2[(k0 + j) * D_OUT + n]);
#pragma unroll
        for (int j = 0; j < 8; j++) W2s[g * 512 + l * 8 + j] = v[j];
    }
}

// R10: X-DELIVERY experiment. Never varied in R0-R9: the x fragment load is a
// 64-segment gather per instruction (lane stride 512 B), 16 per wave at the
// HEAD of every tile chain; request-count x L3/HBM latency against per-CU
// MSHRs is invisible to all captured counters and explains both flatness and
// the TLP null. Now: 16 STRUCTURED loads (8 contiguous 128-B chunks each,
// ~8x fewer segments), hoisted+independent -> cvt_pk bf16 -> ds_write_b64 to
// a wave-private [32][40] scratch -> ds_read_b128 fragments (in-order DS
// pipe, R0-R4-proven; aligned; <=4-way conflicts, free-ish). Counts scan:
// 31-iter dependent-LDS loop -> __ballot + ctz (no loop). Core = R5 verbatim.
__global__ __launch_bounds__(768, 3) void ds_main(
    const float* __restrict__ x, const int* __restrict__ seg,
    const unsigned short* __restrict__ W1s, const float* __restrict__ b1,
    const unsigned short* __restrict__ W2s, const float* __restrict__ b2,
    float* __restrict__ out, float* __restrict__ counts)
{
    __shared__ __align__(16) unsigned short wbuf[128 * 512];     // 128 KB: frags 0..63 W1, 64..127 W2
    __shared__ __align__(16) unsigned short xstg[12][32][40];    // 30 KB: per-wave x bounce [tok][col+pad]
    __shared__ int ssegs[12][32];

    const int tid = threadIdx.x;
    const int wave = tid >> 6, lane = tid & 63;
    const int hl = lane >> 5, c31 = lane & 31;
    const int tok0 = blockIdx.x * 384 + wave * 32;
    const bool active = (tok0 < T_TOTAL);          // wave-uniform tail guard

    // ---- one-time weight staging by waves 0..7 (16B/lane, linear) ----
    if (wave < 8) {
#pragma unroll
        for (int i = 0; i < 8; i++) {
            __builtin_amdgcn_global_load_lds((gu32*)(W1s + i * 4096 + tid * 8),
                                             (lu32*)(wbuf + i * 4096 + tid * 8), 16, 0, 0);
            __builtin_amdgcn_global_load_lds((gu32*)(W2s + i * 4096 + tid * 8),
                                             (lu32*)(wbuf + 32768 + i * 4096 + tid * 8), 16, 0, 0);
        }
    }

    int* sseg = ssegs[wave];
    unsigned short* xs = &xstg[wave][0][0];

    // ---- x: structured loads (instr = 8 tokens' contiguous 128-B chunks) ----
    // instr (c4,i): lane l -> token i*8+(l>>3), f32 cols c4*32 + 4*(l&7) .. +3
    float4 xv[16];
    short8 xfa[8];
    if (active) {
        if (lane < 32) sseg[lane] = seg[tok0 + lane];
        const int tsub = lane >> 3, csub = lane & 7;
#pragma unroll
        for (int c4 = 0; c4 < 4; c4++)
#pragma unroll
            for (int i = 0; i < 4; i++)
                xv[c4 * 4 + i] = *(const float4*)(
                    x + (size_t)(tok0 + i * 8 + tsub) * D_IN + c4 * 32 + csub * 4);

        // ---- bounce: cvt -> ds_write_b64 -> ds_read_b128 fragments ----
#pragma unroll
        for (int c4 = 0; c4 < 4; c4++) {
#pragma unroll
            for (int i = 0; i < 4; i++) {
                float4 v = xv[c4 * 4 + i];
                unsigned p0, p1;
                asm("v_cvt_pk_bf16_f32 %0, %1, %2" : "=v"(p0) : "v"(v.x), "v"(v.y));
                asm("v_cvt_pk_bf16_f32 %0, %1, %2" : "=v"(p1) : "v"(v.z), "v"(v.w));
                uint2v w; w[0] = p0; w[1] = p1;
                // row = i*8+tsub, halfword col = 4*csub  (byte = row*80 + csub*8, 8-B aligned)
                *(__attribute__((address_space(3))) uint2v*)
                    ((__attribute__((address_space(3))) unsigned short*)(xs) +
                     (i * 8 + tsub) * 40 + csub * 4) = w;
            }
            // frags 2*c4, 2*c4+1: lane l reads its token (l&31), 16 B (in-order DS pipe)
#pragma unroll
            for (int cc = 0; cc < 2; cc++)
                xfa[c4 * 2 + cc] = *(const short8*)(xs + (lane & 31) * 40 + cc * 16 + hl * 8);
        }
    }

    floatx16 acc2[4];
#pragma unroll
    for (int o = 0; o < 4; o++)
#pragma unroll
        for (int i = 0; i < 16; i++) acc2[o][i] = 0.f;

    __syncthreads();   // weights staged; ONLY barrier
    if (!active) return;

    // ---- fused pipeline over 8 h1 col-tiles (R5 core, verbatim) ----
#pragma unroll
    for (int nt = 0; nt < 8; nt++) {
        floatx16 acc1;
#pragma unroll
        for (int i = 0; i < 16; i++) acc1[i] = 0.f;
#pragma unroll
        for (int c = 0; c < 8; c++) {
            short8 wf = *(const short8*)(wbuf + (nt * 8 + c) * 512 + lane * 8);
            acc1 = __builtin_amdgcn_mfma_f32_32x32x16_bf16(wf, xfa[c], acc1, 0, 0, 0);
        }
        float v[16];
#pragma unroll
        for (int g = 0; g < 4; g++) {
            floatx4 bv = *(const floatx4*)(b1 + nt * 32 + g * 8 + hl * 4);
#pragma unroll
            for (int i = 0; i < 4; i++) v[g * 4 + i] = fmaxf(acc1[g * 4 + i] + bv[i], 0.f);
        }
        unsigned int pk[8];
#pragma unroll
        for (int p = 0; p < 8; p++)
            asm("v_cvt_pk_bf16_f32 %0, %1, %2" : "=v"(pk[p]) : "v"(v[2 * p]), "v"(v[2 * p + 1]));
#pragma unroll
        for (int s = 0; s < 2; s++) {
            unsigned int d0 = pk[s * 4 + 0], d2 = pk[s * 4 + 2];
            asm("v_permlane32_swap_b32 %0, %1" : "+v"(d0), "+v"(d2));
            unsigned int d1 = pk[s * 4 + 1], d3 = pk[s * 4 + 3];
            asm("v_permlane32_swap_b32 %0, %1" : "+v"(d1), "+v"(d3));
            U8 u; u.u = (uint4v){d0, d1, d2, d3};
            const short8 hf = u.s;
            const int c2 = nt * 2 + s;
#pragma unroll
            for (int o = 0; o < 4; o++) {
                short8 bw = *(const short8*)(wbuf + (64 + o * 16 + c2) * 512 + lane * 8);
                acc2[o] = __builtin_amdgcn_mfma_f32_32x32x16_bf16(hf, bw, acc2[o], 0, 0, 0);
            }
        }
    }

    // ---- counts: ballot-based run heads + lengths (no serial LDS loop) ----
    {
        int s_l = (lane < 32) ? sseg[lane] : 0;
        int s_p = (lane > 0 && lane < 32) ? sseg[lane - 1] : -1;
        bool head = (lane < 32) && (lane == 0 || s_p != s_l);
        unsigned long long bal = __ballot(head);       // bits >=32 are 0
        if (head) {
            unsigned long long rest = bal >> (lane + 1);
            int next = rest ? (lane + 1 + __builtin_ctzll(rest)) : 32;
            atomicAdd(&counts[s_l], (float)(next - lane));
        }
    }

    // ---- epilogue: lane owns outcol per o-tile; swaps -> contiguous 16 toks; run-scan ----
    int sid[16];
#pragma unroll
    for (int e = 0; e < 16; e++) sid[e] = sseg[hl * 16 + e];

#pragma unroll
    for (int o = 0; o < 4; o++) {
        const float bias = b2[o * 32 + c31];
        float val[16];
#pragma unroll
        for (int r = 0; r < 16; r++) val[r] = fmaxf(acc2[o][r] + bias, 0.f);
        float st[16];
#pragma unroll
        for (int i = 0; i < 4; i++) {
            float a = val[i], b = val[8 + i];
            asm("v_permlane32_swap_b32 %0, %1" : "+v"(a), "+v"(b));
            st[i] = a; st[4 + i] = b;
            float c = val[4 + i], d = val[12 + i];
            asm("v_permlane32_swap_b32 %0, %1" : "+v"(c), "+v"(d));
            st[8 + i] = c; st[12 + i] = d;
        }
        const int col = o * 32 + c31;
        float sum = st[0];
#pragma unroll
        for (int e = 1; e < 16; e++) {
            if (sid[e] != sid[e - 1]) {
                atomicAdd(&out[(size_t)sid[e - 1] * D_OUT + col], sum);
                sum = 0.f;
            }
            sum += st[e];
        }
        atomicAdd(&out[(size_t)sid[15] * D_OUT + col], sum);
    }
}

__global__ void div_kernel(float4* __restrict__ out4, const float* __restrict__ counts) {
    int i = blockIdx.x * 256 + threadIdx.x;   // 262144 float4s, 32 per row
    float inv = 1.f / fmaxf(counts[i >> 5], 1.f);
    float4 v = out4[i];
    v.x *= inv; v.y *= inv; v.z *= inv; v.w *= inv;
    out4[i] = v;
}

extern "C" void kernel_launch(void* const* d_in, const int* in_sizes, int n_in,
                              void* d_out, int out_size, void* d_ws, size_t ws_size,
                              hipStream_t stream) {
    const float* x  = (const float*)d_in[0];
    const int* seg  = (const int*)d_in[1];
    const float* W1 = (const float*)d_in[3];
    const float* b1 = (const float*)d_in[4];
    const float* W2 = (const float*)d_in[5];
    const float* b2 = (const float*)d_in[6];
    float* out = (float*)d_out;

    float* counts       = (float*)d_ws;                                   // 32 KB
    unsigned short* W1s = (unsigned short*)((char*)d_ws + 32768);         // 64 KB
    unsigned short* W2s = (unsigned short*)((char*)d_ws + 32768 + 65536); // 64 KB

    hipMemsetAsync(out, 0, (size_t)N_SETS * D_OUT * sizeof(float), stream);
    hipMemsetAsync(counts, 0, (size_t)N_SETS * sizeof(float), stream);
    hipLaunchKernelGGL(setup_kernel, dim3(32), dim3(256), 0, stream,
                       W1, W2, W1s, W2s);
    hipLaunchKernelGGL(ds_main, dim3(683), dim3(768), 0, stream,
                       x, seg, W1s, b1, W2s, b2, out, counts);
    hipLaunchKernelGGL(div_kernel, dim3(1024), dim3(256), 0, stream,
                       (float4*)out, counts);
}